// Round 1
// baseline (800.366 us; speedup 1.0000x reference)
//
#include <hip/hip_runtime.h>
#include <math.h>

#define BS 256
#define V 10475
#define NJ 55
#define R3 31425      // V*3
#define NP 486        // 54*9
#define LB 60         // effective betas (10 shape + 50 expression)
#define JOFF 8044800  // BS*R3 — joints output offset
#define RT 16         // rows per block in k_vposed

__device__ const int PARENTS_d[NJ] = {
  -1, 0, 0, 0, 1, 2, 3, 4, 5, 6, 7, 8, 9, 9, 9, 12, 13, 14, 16, 17, 18, 19,
  15, 15, 15, 20, 25, 26, 20, 28, 29, 20, 31, 32, 20, 34, 35, 20, 37, 38,
  21, 40, 41, 21, 43, 44, 21, 46, 47, 21, 49, 50, 21, 52, 53
};

// ---------------- K1: rodrigues + pose_feature^T + betas^T ----------------
__global__ __launch_bounds__(256) void k_pose(
    const float* __restrict__ pose, const float* __restrict__ shp,
    const float* __restrict__ expr, const float* __restrict__ go,
    float* __restrict__ rot_ws, float* __restrict__ pf_T,
    float* __restrict__ betas_T) {
  int b = threadIdx.x;
  int j = blockIdx.x;
  if (j == NJ) {  // betas builder block
    #pragma unroll
    for (int l = 0; l < 10; ++l) betas_T[l * BS + b] = shp[b * 10 + l];
    #pragma unroll
    for (int l = 0; l < 50; ++l) betas_T[(10 + l) * BS + b] = expr[b * 50 + l];
    return;
  }
  float rx, ry, rz;
  if (j == 0) { rx = go[0]; ry = go[1]; rz = go[2]; }
  else if (j == 23 || j == 24) { rx = 0.f; ry = 0.f; rz = 0.f; }
  else {
    int src = (j <= 21) ? j : (j == 22 ? 52 : j - 3);
    const float* p = pose + ((size_t)b * 53 + src) * 3;
    rx = p[0]; ry = p[1]; rz = p[2];
  }
  float sx = rx + 1e-8f, sy = ry + 1e-8f, sz = rz + 1e-8f;
  float ang = sqrtf(sx * sx + sy * sy + sz * sz);
  float inv = 1.f / ang;
  float x = rx * inv, y = ry * inv, z = rz * inv;
  float s = sinf(ang), c = cosf(ang), C = 1.f - c;
  float R[9];
  R[0] = 1.f - C * (y * y + z * z);
  R[1] = -s * z + C * x * y;
  R[2] =  s * y + C * x * z;
  R[3] =  s * z + C * x * y;
  R[4] = 1.f - C * (x * x + z * z);
  R[5] = -s * x + C * y * z;
  R[6] = -s * y + C * x * z;
  R[7] =  s * x + C * y * z;
  R[8] = 1.f - C * (x * x + y * y);
  float* rw = rot_ws + ((size_t)b * NJ + j) * 9;
  #pragma unroll
  for (int e = 0; e < 9; ++e) rw[e] = R[e];
  if (j >= 1) {
    int pb = (j - 1) * 9;
    #pragma unroll
    for (int e = 0; e < 9; ++e)
      pf_T[(pb + e) * BS + b] = R[e] - ((e == 0 || e == 4 || e == 8) ? 1.f : 0.f);
  }
}

// ---------------- K2: JS[j][c][61] = J_reg @ [shapedirs_slice | v_template] --
__global__ __launch_bounds__(256) void k_js(
    const float* __restrict__ Jreg, const float* __restrict__ sd,
    const float* __restrict__ vt, float* __restrict__ JS) {
  int j = blockIdx.x, c = blockIdx.y;
  int tid = threadIdx.x;
  int lane = tid & 63;
  int g = (tid >> 6) + 4 * blockIdx.z;  // 0..31 across z
  int col = (lane < 10) ? lane : (lane < 60 ? 300 + (lane - 10) : -1);
  float acc = 0.f;
  #pragma unroll 4
  for (int v = g; v < V; v += 32) {
    float w = Jreg[(size_t)j * V + v];
    float xv;
    if (col >= 0)        xv = sd[((size_t)v * 3 + c) * 350 + col];
    else if (lane == 60) xv = vt[(size_t)v * 3 + c];
    else                 xv = 0.f;
    acc += w * xv;
  }
  __shared__ float red[256];
  red[tid] = acc;
  __syncthreads();
  if (tid < 64) {
    float sres = red[tid] + red[tid + 64] + red[tid + 128] + red[tid + 192];
    if (tid <= 60) atomicAdd(&JS[((size_t)j * 3 + c) * 61 + tid], sres);
  }
}

// ---------------- K3: joints + kinematic chain + A_rel --------------------
__global__ __launch_bounds__(64) void k_chain(
    const float* __restrict__ JS, const float* __restrict__ betas_T,
    const float* __restrict__ rot_ws, float* __restrict__ arel,
    float* __restrict__ out) {
  int b = blockIdx.x;
  int lane = threadIdx.x;
  __shared__ float joints_l[165];
  __shared__ float Tl[880];
  __shared__ float A[880];
  // joints[b] = JS @ [betas|1]
  for (int idx = lane; idx < 165; idx += 64) {
    float sacc = JS[idx * 61 + 60];  // v_template column, beta = 1
    #pragma unroll
    for (int l = 0; l < LB; ++l) sacc += JS[idx * 61 + l] * betas_T[l * BS + b];
    joints_l[idx] = sacc;
  }
  __syncthreads();
  // T_local
  for (int idx = lane; idx < 880; idx += 64) {
    int j = idx >> 4, e = idx & 15, r = e >> 2, c = e & 3;
    float val;
    if (r < 3) {
      if (c < 3) val = rot_ws[((size_t)b * NJ + j) * 9 + r * 3 + c];
      else {
        int par = PARENTS_d[j];
        val = joints_l[j * 3 + r] - (par >= 0 ? joints_l[par * 3 + r] : 0.f);
      }
    } else val = (c == 3) ? 1.f : 0.f;
    Tl[idx] = val;
  }
  __syncthreads();
  if (lane < 16) A[lane] = Tl[lane];
  __syncthreads();
  for (int j = 1; j < NJ; ++j) {
    int par = PARENTS_d[j];
    if (lane < 16) {
      int r = lane >> 2, c = lane & 3;
      float sacc = 0.f;
      #pragma unroll
      for (int k = 0; k < 4; ++k)
        sacc += A[par * 16 + r * 4 + k] * Tl[j * 16 + k * 4 + c];
      A[j * 16 + lane] = sacc;
    }
    __syncthreads();
  }
  // posed_joints output
  for (int idx = lane; idx < 165; idx += 64) {
    int j = idx / 3, r = idx % 3;
    out[JOFF + (size_t)b * 165 + idx] = A[j * 16 + r * 4 + 3];
  }
  // A_rel (rotation 9 + adjusted translation 3)
  for (int idx = lane; idx < 660; idx += 64) {
    int j = idx / 12, e = idx % 12;
    float val;
    if (e < 9) { int r = e / 3, c = e % 3; val = A[j * 16 + r * 4 + c]; }
    else {
      int r = e - 9;
      val = A[j * 16 + r * 4 + 3]
          - (A[j * 16 + r * 4 + 0] * joints_l[j * 3 + 0] +
             A[j * 16 + r * 4 + 1] * joints_l[j * 3 + 1] +
             A[j * 16 + r * 4 + 2] * joints_l[j * 3 + 2]);
    }
    arel[(size_t)b * 660 + idx] = val;
  }
}

// ---------------- K4: v_posed = v_template + S·betas + P·pose_feature -----
// thread = batch, block handles RT=16 consecutive rows of (v,c)-flattened dim
__global__ __launch_bounds__(256) void k_vposed(
    const float* __restrict__ vt, const float* __restrict__ sd,
    const float* __restrict__ pd, const float* __restrict__ betas_T,
    const float* __restrict__ pf_T, float* __restrict__ out) {
  int b = threadIdx.x;
  int r0 = blockIdx.x * RT;
  float bet[LB];
  #pragma unroll
  for (int l = 0; l < LB; ++l) bet[l] = betas_T[l * BS + b];
  float acc[RT];
  #pragma unroll
  for (int i = 0; i < RT; ++i) acc[i] = 0.f;

  if (r0 + RT <= R3) {  // full block (all but the last)
    #pragma unroll
    for (int i = 0; i < RT; ++i) {
      int row = r0 + i;
      const float* sdr = sd + (size_t)row * 350;
      float a = vt[row];
      #pragma unroll
      for (int l = 0; l < 10; ++l) a += sdr[l] * bet[l];
      #pragma unroll
      for (int l = 0; l < 50; ++l) a += sdr[300 + l] * bet[10 + l];
      acc[i] = a;
    }
    #pragma unroll 2
    for (int p = 0; p < NP; ++p) {
      float pf = pf_T[p * BS + b];
      const float* pdr = pd + (size_t)p * R3 + r0;
      #pragma unroll
      for (int i = 0; i < RT; ++i) acc[i] += pdr[i] * pf;
    }
  } else {
    int nrow = R3 - r0;
    for (int i = 0; i < nrow; ++i) {
      int row = r0 + i;
      const float* sdr = sd + (size_t)row * 350;
      float a = vt[row];
      for (int l = 0; l < 10; ++l) a += sdr[l] * bet[l];
      for (int l = 0; l < 50; ++l) a += sdr[300 + l] * bet[10 + l];
      for (int p = 0; p < NP; ++p) a += pd[(size_t)p * R3 + row] * pf_T[p * BS + b];
      acc[i] = a;
    }
  }
  // LDS transpose for coalesced global writes
  __shared__ float tile[BS * 17];
  #pragma unroll
  for (int i = 0; i < RT; ++i) tile[b * 17 + i] = acc[i];
  __syncthreads();
  for (int idx = b; idx < BS * RT; idx += BS) {
    int bb = idx >> 4, i = idx & 15;
    int row = r0 + i;
    if (row < R3) out[(size_t)bb * R3 + row] = tile[bb * 17 + i];
  }
}

// ---------------- K5: skinning (reads v_posed from d_out in place) --------
__global__ __launch_bounds__(256) void k_skin(
    const float* __restrict__ lbs, const float* __restrict__ arel,
    float* __restrict__ out) {
  int v = blockIdx.x * 256 + threadIdx.x;
  bool valid = v < V;
  float w[NJ];
  if (valid) {
    #pragma unroll
    for (int j = 0; j < NJ; ++j) w[j] = lbs[(size_t)v * NJ + j];
  }
  int b0 = blockIdx.y * 4;
  for (int bi = 0; bi < 4; ++bi) {
    int b = b0 + bi;
    const float* __restrict__ ar = arel + (size_t)b * 660;  // block-uniform → s_loads
    if (valid) {
      float T[12];
      #pragma unroll
      for (int e = 0; e < 12; ++e) T[e] = 0.f;
      for (int j = 0; j < NJ; ++j) {
        float wj = w[j];
        #pragma unroll
        for (int e = 0; e < 12; ++e) T[e] += wj * ar[j * 12 + e];
      }
      float* vp = out + (size_t)b * R3 + v * 3;
      float x = vp[0], y = vp[1], z = vp[2];
      vp[0] = T[0] * x + T[1] * y + T[2] * z + T[9];
      vp[1] = T[3] * x + T[4] * y + T[5] * z + T[10];
      vp[2] = T[6] * x + T[7] * y + T[8] * z + T[11];
    }
  }
}

extern "C" void kernel_launch(void* const* d_in, const int* in_sizes, int n_in,
                              void* d_out, int out_size, void* d_ws, size_t ws_size,
                              hipStream_t stream) {
  const float* pose = (const float*)d_in[0];
  const float* shp  = (const float*)d_in[1];
  const float* expr = (const float*)d_in[2];
  const float* go   = (const float*)d_in[3];
  const float* vt   = (const float*)d_in[4];
  const float* sd   = (const float*)d_in[5];
  const float* pd   = (const float*)d_in[6];
  const float* jr   = (const float*)d_in[7];
  const float* lbs  = (const float*)d_in[8];
  float* out = (float*)d_out;
  float* ws  = (float*)d_ws;

  float* betas_T = ws;                  // 60*256      = 15360 floats
  float* pf_T    = betas_T + 15360;     // 486*256     = 124416
  float* rot_ws  = pf_T + 124416;       // 256*55*9    = 126720
  float* JS      = rot_ws + 126720;     // 165*61      = 10065 (pad to 10080)
  float* arel    = JS + 10080;          // 256*55*12   = 168960
  // total ~1.78 MB of d_ws

  hipMemsetAsync(JS, 0, 10080 * sizeof(float), stream);
  k_pose<<<NJ + 1, 256, 0, stream>>>(pose, shp, expr, go, rot_ws, pf_T, betas_T);
  k_js<<<dim3(NJ, 3, 8), 256, 0, stream>>>(jr, sd, vt, JS);
  k_chain<<<BS, 64, 0, stream>>>(JS, betas_T, rot_ws, arel, out);
  k_vposed<<<(R3 + RT - 1) / RT, 256, 0, stream>>>(vt, sd, pd, betas_T, pf_T, out);
  k_skin<<<dim3((V + 255) / 256, BS / 4), 256, 0, stream>>>(lbs, arel, out);
}